// Round 15
// baseline (6514.074 us; speedup 1.0000x reference)
//
#include <hip/hip_runtime.h>
#include <hip/hip_bf16.h>

// EA-LSTM for MI355X (gfx950), round 15: persistent kernel with IN-KERNEL
// chunked precompute of the x-projections.
// B=128, T=2048, DYN=8, STAT=24, H=256, OUT=1.
// 32 WGs x 512 thr (8 waves, 2/SIMD). Batch row b staged at A-row 4b (MFMA D
// r==0 -> 1 gate-set per lane,nt); wave w owns ch [w*32,w*32+32).
// Phase A (per chunk of TC steps): each wave GEMM-precomputes P[tl][row][lr] =
//   16B = [f,f,g,g,o,o,i,i] bf16 (x-proj + ALL biases; sigm applied to i) into
//   its PRIVATE ws region (same-wave write->read; vmcnt(0) between phases).
// Phase B (t-loop): 48 MFMAs/wave (f,g ks0..7 + o ks0..6 regs, o-ks7 LDS),
//   10 LDS b128/wave/step, one 16B P load (prefetched 2 deep), lgkm-only
//   barrier, setprio around MFMAs, po 2-step reduce, wave0 finalize.
// Fallback (ws < 16MB): round-14 kernel (proven 2806us).

#define T_LEN 2048
#define HD 256

typedef __attribute__((ext_vector_type(8))) short bf16x8;
typedef __attribute__((ext_vector_type(4))) float f32x4;
typedef __attribute__((ext_vector_type(4))) unsigned int u32x4;

#define LOG2E 1.4426950408889634f

__device__ __forceinline__ short f2bf(float f) {
  unsigned u = __float_as_uint(f);
  unsigned r = (u + 0x7fffu + ((u >> 16) & 1u)) >> 16;
  return (short)r;
}

__device__ __forceinline__ bf16x8 loadw8(const float* p) {
  bf16x8 r;
#pragma unroll
  for (int i = 0; i < 8; ++i) r[i] = f2bf(p[i]);
  return r;
}

__device__ __forceinline__ bf16x8 loadw8v(const float* p) {
  const float4 v0 = *reinterpret_cast<const float4*>(p);
  const float4 v1 = *reinterpret_cast<const float4*>(p + 4);
  bf16x8 r;
  r[0] = f2bf(v0.x); r[1] = f2bf(v0.y); r[2] = f2bf(v0.z); r[3] = f2bf(v0.w);
  r[4] = f2bf(v1.x); r[5] = f2bf(v1.y); r[6] = f2bf(v1.z); r[7] = f2bf(v1.w);
  return r;
}

__device__ __forceinline__ float sigm(float x) {
  float e = __builtin_amdgcn_exp2f(-LOG2E * x);
  return __builtin_amdgcn_rcpf(1.0f + e);
}

// clamp-free tanh: 1 - 2/(e^{2x}+1); saturates to +/-1, NaN-free.
__device__ __forceinline__ float tanh_(float x) {
  float e = __builtin_amdgcn_exp2f((2.0f * LOG2E) * x);
  return 1.0f - 2.0f * __builtin_amdgcn_rcpf(e + 1.0f);
}

// bf16 short idx (0..7) out of a 16B packed block
__device__ __forceinline__ float punp16(u32x4 p, int idx) {
  unsigned d = p[idx >> 1];
  return __uint_as_float((idx & 1) ? (d & 0xffff0000u) : (d << 16));
}

// Workgroup barrier draining ONLY LDS ops (not vmem).
__device__ __forceinline__ void wg_barrier_lgkm() {
  asm volatile("s_waitcnt lgkmcnt(0)" ::: "memory");
  __builtin_amdgcn_s_barrier();
  __builtin_amdgcn_sched_barrier(0);
}

// ====================== main kernel (in-kernel precompute) ======================
// A tile: 16 rows x 264 cols bf16 (h only). Valid batch rows at A-rows {0,4,8,12}.
#define ASTR 264
#define ABUF (16 * ASTR)

__global__ __launch_bounds__(512, 2) void ealstm_pp(
    const float* __restrict__ x, const float* __restrict__ c0, const float* __restrict__ h0,
    const float* __restrict__ Wi, const float* __restrict__ bi,
    const float* __restrict__ Wfx, const float* __restrict__ bfx,
    const float* __restrict__ Wfh, const float* __restrict__ bfh,
    const float* __restrict__ Wgx, const float* __restrict__ bgx,
    const float* __restrict__ Wgh, const float* __restrict__ bgh,
    const float* __restrict__ Wox, const float* __restrict__ box_,
    const float* __restrict__ Woh, const float* __restrict__ boh,
    const float* __restrict__ Wout, const float* __restrict__ bout,
    float* __restrict__ out, unsigned short* __restrict__ P, int tc)
{
  __shared__ __attribute__((aligned(16))) short A_sh[2 * ABUF];       // 16896 B
  __shared__ __attribute__((aligned(16))) short Bo7_sh[8 * 2 * 512];  // 16384 B
  __shared__ float out_part[2][4][32];                                // 1024 B

  const int tid = threadIdx.x;
  const int w   = tid >> 6;   // wave 0..7, owns ch [w*32, w*32+32)
  const int l   = tid & 63;
  const int lr  = l & 15;
  const int lg  = l >> 4;     // activation row = lg (A-row trick)
  const int n0  = w * 32;
  const int wg  = blockIdx.x; // 4-row batch block

  // ---- x-projection B-frags + combined biases (for precompute phases) ----
  bf16x8 Bw[4][2];
  float cb[4][2];
  {
    bf16x8 z = (bf16x8)(short)0;
#pragma unroll
    for (int nt = 0; nt < 2; ++nt) {
      const int n = n0 + nt * 16 + lr;
      Bw[0][nt] = (lg == 0) ? loadw8(Wfx + n * 8) : z;
      Bw[1][nt] = (lg == 0) ? loadw8(Wgx + n * 8) : z;
      Bw[2][nt] = (lg == 0) ? loadw8(Wox + n * 8) : z;
      Bw[3][nt] = (lg >= 1) ? loadw8(Wi + n * 24 + (lg - 1) * 8) : z;
      cb[0][nt] = bfx[n] + bfh[n];
      cb[1][nt] = bgx[n] + bgh[n];
      cb[2][nt] = box_[n] + boh[n];
      cb[3][nt] = bi[n];
    }
  }

  // ---- register-resident recurrent weights: f,g ks0..7; o ks0..6 ----
  bf16x8 Bf[8][2], Bg[8][2], Bo[7][2];
#pragma unroll
  for (int ks = 0; ks < 8; ++ks) {
#pragma unroll
    for (int nt = 0; nt < 2; ++nt) {
      const int n = n0 + nt * 16 + lr;
      const int k = ks * 32 + lg * 8;
      Bf[ks][nt] = loadw8(Wfh + n * HD + k);
      Bg[ks][nt] = loadw8(Wgh + n * HD + k);
      if (ks < 7) Bo[ks][nt] = loadw8(Woh + n * HD + k);
    }
  }
  // ---- LDS-resident: o ks7 ----
  short* bo7 = Bo7_sh + w * 1024;
#pragma unroll
  for (int nt = 0; nt < 2; ++nt) {
    const int n = n0 + nt * 16 + lr;
    bf16x8 fr = loadw8(Woh + n * HD + 7 * 32 + lg * 8);
    *reinterpret_cast<bf16x8*>(bo7 + nt * 512 + l * 8) = fr;
  }

  // ---- Wout, c-state ----
  float woutv[2], cst[2];
#pragma unroll
  for (int nt = 0; nt < 2; ++nt) {
    const int n = n0 + nt * 16 + lr;
    woutv[nt] = Wout[n];
    cst[nt]   = c0[n];
  }
  const float boutv = bout[0];

  // ---- zero both A buffers; stage h0 at A-rows {0,4,8,12} ----
  for (int idx = tid; idx < 2 * ABUF; idx += 512) A_sh[idx] = 0;
  __syncthreads();
  for (int idx = tid; idx < 4 * 256; idx += 512) {
    A_sh[(4 * (idx >> 8)) * ASTR + (idx & 255)] = f2bf(h0[idx & 255]);
  }
  __syncthreads();

  // wave-private P region: tc slots x 512 shorts (4 rows x 16 lr x 8)
  unsigned short* Pw = P + ((size_t)wg * 8 + w) * ((size_t)tc * 512);
  const unsigned short* Pr = Pw + ((size_t)lg * 16 + lr) * 8;  // + tl*512
  const int akoff = lg * 8;
  const f32x4 z4 = {0.f, 0.f, 0.f, 0.f};

  for (int t0c = 0; t0c < T_LEN; t0c += tc) {
    // ================= Phase A: precompute P for [t0c, t0c+tc) =================
    const int ntiles = tc >> 2;  // 4 rows x tc/16 tiles
#pragma unroll 1
    for (int tile = 0; tile < ntiles; ++tile) {
      const int row  = tile & 3;
      const int trow = (tile >> 2) << 4;
      const float* xr = x + ((size_t)(wg * 4 + row) * T_LEN + t0c + trow + lr) * 32 + akoff;
      const bf16x8 a = loadw8v(xr);
      f32x4 acc[4][2];
#pragma unroll
      for (int g = 0; g < 4; ++g) {
#pragma unroll
        for (int nt = 0; nt < 2; ++nt) {
          f32x4 cbs; cbs[0] = cb[g][nt]; cbs[1] = cb[g][nt]; cbs[2] = cb[g][nt]; cbs[3] = cb[g][nt];
          acc[g][nt] = __builtin_amdgcn_mfma_f32_16x16x32_bf16(a, Bw[g][nt], cbs, 0, 0, 0);
        }
      }
#pragma unroll
      for (int r = 0; r < 4; ++r) {
        bf16x8 pk;
        pk[0] = f2bf(acc[0][0][r]); pk[1] = f2bf(acc[0][1][r]);
        pk[2] = f2bf(acc[1][0][r]); pk[3] = f2bf(acc[1][1][r]);
        pk[4] = f2bf(acc[2][0][r]); pk[5] = f2bf(acc[2][1][r]);
        pk[6] = f2bf(sigm(acc[3][0][r])); pk[7] = f2bf(sigm(acc[3][1][r]));
        *reinterpret_cast<bf16x8*>(Pw + ((size_t)(trow + lg * 4 + r) * 4 + row) * 128 + lr * 8) = pk;
      }
    }
    asm volatile("s_waitcnt vmcnt(0)" ::: "memory");  // own-wave P writes -> reads

    // prefetch P for tl = 0, 1
    u32x4 pc = *reinterpret_cast<const u32x4*>(Pr);
    u32x4 pn = *reinterpret_cast<const u32x4*>(Pr + ((tc > 1) ? 512 : 0));

    // ================= Phase B: recurrence over the chunk =================
#pragma unroll 1
    for (int tl = 0; tl < tc; ++tl) {
      const int t   = t0c + tl;
      const int cur = t & 1;
      const short* ArowC = A_sh + cur * ABUF + lr * ASTR;
      short* Anxt = A_sh + (cur ^ 1) * ABUF;

      // prefetch P for tl+2 (clamped within chunk)
      const int t2 = (tl + 2 < tc) ? (tl + 2) : (tc - 1);
      const u32x4 p2 = *reinterpret_cast<const u32x4*>(Pr + (size_t)t2 * 512);

      // finalize previous step's output (hidden under this step's MFMA phase)
      if (t > 0 && w == 0 && l < 4) {
        float s = boutv;
#pragma unroll
        for (int ww = 0; ww < 32; ++ww) s += out_part[cur ^ 1][l][ww];
        out[(size_t)(wg * 4 + l) * T_LEN + (t - 1)] = s;
      }

      // ---- h K-loop (48 MFMAs); setprio around the cluster ----
      f32x4 acc[3][2];
      const bf16x8 a0 = *reinterpret_cast<const bf16x8*>(ArowC + 0 * 32 + akoff);
      const bf16x8 a1 = *reinterpret_cast<const bf16x8*>(ArowC + 1 * 32 + akoff);
      const bf16x8 a2 = *reinterpret_cast<const bf16x8*>(ArowC + 2 * 32 + akoff);
      const bf16x8 a3 = *reinterpret_cast<const bf16x8*>(ArowC + 3 * 32 + akoff);
      __builtin_amdgcn_s_setprio(1);
      {
        acc[0][0] = __builtin_amdgcn_mfma_f32_16x16x32_bf16(a0, Bf[0][0], z4, 0, 0, 0);
        acc[0][1] = __builtin_amdgcn_mfma_f32_16x16x32_bf16(a0, Bf[0][1], z4, 0, 0, 0);
        acc[1][0] = __builtin_amdgcn_mfma_f32_16x16x32_bf16(a0, Bg[0][0], z4, 0, 0, 0);
        acc[1][1] = __builtin_amdgcn_mfma_f32_16x16x32_bf16(a0, Bg[0][1], z4, 0, 0, 0);
        acc[2][0] = __builtin_amdgcn_mfma_f32_16x16x32_bf16(a0, Bo[0][0], z4, 0, 0, 0);
        acc[2][1] = __builtin_amdgcn_mfma_f32_16x16x32_bf16(a0, Bo[0][1], z4, 0, 0, 0);
      }
      {
        const bf16x8 aa[3] = {a1, a2, a3};
#pragma unroll
        for (int ks = 1; ks < 4; ++ks) {
          const bf16x8 a = aa[ks - 1];
          acc[0][0] = __builtin_amdgcn_mfma_f32_16x16x32_bf16(a, Bf[ks][0], acc[0][0], 0, 0, 0);
          acc[0][1] = __builtin_amdgcn_mfma_f32_16x16x32_bf16(a, Bf[ks][1], acc[0][1], 0, 0, 0);
          acc[1][0] = __builtin_amdgcn_mfma_f32_16x16x32_bf16(a, Bg[ks][0], acc[1][0], 0, 0, 0);
          acc[1][1] = __builtin_amdgcn_mfma_f32_16x16x32_bf16(a, Bg[ks][1], acc[1][1], 0, 0, 0);
          acc[2][0] = __builtin_amdgcn_mfma_f32_16x16x32_bf16(a, Bo[ks][0], acc[2][0], 0, 0, 0);
          acc[2][1] = __builtin_amdgcn_mfma_f32_16x16x32_bf16(a, Bo[ks][1], acc[2][1], 0, 0, 0);
        }
      }
#pragma unroll
      for (int ks = 4; ks < 8; ++ks) {
        const bf16x8 a = *reinterpret_cast<const bf16x8*>(ArowC + ks * 32 + akoff);
        acc[0][0] = __builtin_amdgcn_mfma_f32_16x16x32_bf16(a, Bf[ks][0], acc[0][0], 0, 0, 0);
        acc[0][1] = __builtin_amdgcn_mfma_f32_16x16x32_bf16(a, Bf[ks][1], acc[0][1], 0, 0, 0);
        acc[1][0] = __builtin_amdgcn_mfma_f32_16x16x32_bf16(a, Bg[ks][0], acc[1][0], 0, 0, 0);
        acc[1][1] = __builtin_amdgcn_mfma_f32_16x16x32_bf16(a, Bg[ks][1], acc[1][1], 0, 0, 0);
        if (ks < 7) {
          acc[2][0] = __builtin_amdgcn_mfma_f32_16x16x32_bf16(a, Bo[ks][0], acc[2][0], 0, 0, 0);
          acc[2][1] = __builtin_amdgcn_mfma_f32_16x16x32_bf16(a, Bo[ks][1], acc[2][1], 0, 0, 0);
        } else {
          const bf16x8 b0 = *reinterpret_cast<const bf16x8*>(bo7 + 0 * 512 + l * 8);
          const bf16x8 b1 = *reinterpret_cast<const bf16x8*>(bo7 + 1 * 512 + l * 8);
          acc[2][0] = __builtin_amdgcn_mfma_f32_16x16x32_bf16(a, b0, acc[2][0], 0, 0, 0);
          acc[2][1] = __builtin_amdgcn_mfma_f32_16x16x32_bf16(a, b1, acc[2][1], 0, 0, 0);
        }
      }
      __builtin_amdgcn_s_setprio(0);

      // ---- activations (biases + x-proj live in P; i pre-sigmoided) ----
      float po = 0.0f;
      short hpk[2];
#pragma unroll
      for (int nt = 0; nt < 2; ++nt) {
        const float fpre = acc[0][nt][0] + punp16(pc, 0 + nt);
        const float gpre = acc[1][nt][0] + punp16(pc, 2 + nt);
        const float opre = acc[2][nt][0] + punp16(pc, 4 + nt);
        const float si   = punp16(pc, 6 + nt);
        const float sf = sigm(fpre);
        const float tg = tanh_(gpre);
        const float so = sigm(opre);
        const float c  = sf * cst[nt] + si * tg;
        cst[nt] = c;
        const float hv = so * tanh_(c);
        hpk[nt] = f2bf(hv);
        po += so * woutv[nt];
      }

      // h-writes into ALTERNATE buffer at A-row 4*lg
      Anxt[(4 * lg) * ASTR + (n0 + lr)]      = hpk[0];
      Anxt[(4 * lg) * ASTR + (n0 + 16 + lr)] = hpk[1];

      // po partial-reduce: 2 shuffle steps; 4 partials per (row, wave)
      po += __shfl_xor(po, 1, 64);
      po += __shfl_xor(po, 2, 64);
      if ((lr & 3) == 0) out_part[cur][lg][w * 4 + (lr >> 2)] = po;

      // roll P prefetch
      pc = pn; pn = p2;

      wg_barrier_lgkm();  // single per-step barrier, LDS-drain only
    }
  }

  // final output
  if (w == 0 && l < 4) {
    float s = boutv;
#pragma unroll
    for (int ww = 0; ww < 32; ++ww) s += out_part[(T_LEN - 1) & 1][l][ww];
    out[(size_t)(wg * 4 + l) * T_LEN + (T_LEN - 1)] = s;
  }
}

// ====================== fallback: round-14 kernel (no ws) ======================
#define FASTR 296
#define FABUF (16 * FASTR)

__global__ __launch_bounds__(512, 2) void ealstm_fb(
    const float* __restrict__ x, const float* __restrict__ c0, const float* __restrict__ h0,
    const float* __restrict__ Wi, const float* __restrict__ bi,
    const float* __restrict__ Wfx, const float* __restrict__ bfx,
    const float* __restrict__ Wfh, const float* __restrict__ bfh,
    const float* __restrict__ Wgx, const float* __restrict__ bgx,
    const float* __restrict__ Wgh, const float* __restrict__ bgh,
    const float* __restrict__ Wox, const float* __restrict__ box_,
    const float* __restrict__ Woh, const float* __restrict__ boh,
    const float* __restrict__ Wout, const float* __restrict__ bout,
    float* __restrict__ out)
{
  __shared__ __attribute__((aligned(16))) short A_sh[2 * FABUF];
  __shared__ __attribute__((aligned(16))) short Bx_sh[8 * 8 * 512];
  __shared__ __attribute__((aligned(16))) short Bo7_sh[8 * 2 * 512];
  __shared__ float out_part[2][4][32];

  const int tid = threadIdx.x;
  const int w   = tid >> 6;
  const int l   = tid & 63;
  const int lr  = l & 15;
  const int lg  = l >> 4;
  const int n0  = w * 32;
  const int wg  = blockIdx.x;
  const bool xstage = (tid >= 384);

  bf16x8 Bf[8][2], Bg[8][2], Bo[7][2];
#pragma unroll
  for (int ks = 0; ks < 8; ++ks) {
#pragma unroll
    for (int nt = 0; nt < 2; ++nt) {
      const int n = n0 + nt * 16 + lr;
      const int k = ks * 32 + lg * 8;
      Bf[ks][nt] = loadw8(Wfh + n * HD + k);
      Bg[ks][nt] = loadw8(Wgh + n * HD + k);
      if (ks < 7) Bo[ks][nt] = loadw8(Woh + n * HD + k);
    }
  }
  short* bo7 = Bo7_sh + w * 1024;
#pragma unroll
  for (int nt = 0; nt < 2; ++nt) {
    const int n = n0 + nt * 16 + lr;
    bf16x8 fr = loadw8(Woh + n * HD + 7 * 32 + lg * 8);
    *reinterpret_cast<bf16x8*>(bo7 + nt * 512 + l * 8) = fr;
  }
  short* bxw = Bx_sh + w * 4096;
  {
    bf16x8 z = (bf16x8)(short)0;
    const float* WxArr[3] = {Wfx, Wgx, Wox};
#pragma unroll
    for (int nt = 0; nt < 2; ++nt) {
      const int n = n0 + nt * 16 + lr;
#pragma unroll
      for (int g = 0; g < 3; ++g) {
        bf16x8 fr = (lg == 0) ? loadw8(WxArr[g] + n * 8) : z;
        *reinterpret_cast<bf16x8*>(bxw + (g * 2 + nt) * 512 + l * 8) = fr;
      }
      bf16x8 fi = (lg >= 1) ? loadw8(Wi + n * 24 + (lg - 1) * 8) : z;
      *reinterpret_cast<bf16x8*>(bxw + (6 + nt) * 512 + l * 8) = fi;
    }
  }

  float bias[4][2], woutv[2], cst[2];
#pragma unroll
  for (int nt = 0; nt < 2; ++nt) {
    const int n = n0 + nt * 16 + lr;
    bias[0][nt] = bfx[n] + bfh[n];
    bias[1][nt] = bgx[n] + bgh[n];
    bias[2][nt] = box_[n] + boh[n];
    bias[3][nt] = bi[n];
    woutv[nt] = Wout[n];
    cst[nt] = c0[n];
  }
  const float boutv = bout[0];

  for (int idx = tid; idx < 2 * FABUF; idx += 512) A_sh[idx] = 0;
  __syncthreads();
  for (int idx = tid; idx < 4 * 256; idx += 512) {
    A_sh[(4 * (idx >> 8)) * FASTR + (idx & 255)] = f2bf(h0[idx & 255]);
  }
  if (xstage) {
    const int row = (tid >> 5) & 3, k = tid & 31;
    A_sh[(4 * row) * FASTR + 256 + k] = f2bf(x[((size_t)(wg * 4 + row) * T_LEN) * 32 + k]);
  }
  __syncthreads();

  const float* xp = x + (size_t)(wg * 4 + ((tid >> 5) & 3)) * T_LEN * 32 + (tid & 31);
  const int akoff = lg * 8;
  const f32x4 z4 = {0.f, 0.f, 0.f, 0.f};

  for (int t = 0; t < T_LEN; ++t) {
    const int cur = t & 1;
    const short* ArowC = A_sh + cur * FABUF + lr * FASTR;
    short* Anxt = A_sh + (cur ^ 1) * FABUF;

    if (t > 0 && w == 0 && l < 4) {
      float s = boutv;
#pragma unroll
      for (int ww = 0; ww < 32; ++ww) s += out_part[cur ^ 1][l][ww];
      out[(size_t)(wg * 4 + l) * T_LEN + (t - 1)] = s;
    }

    float xval = 0.0f;
    if (xstage) {
      const int tn = (t + 1 < T_LEN) ? (t + 1) : (T_LEN - 1);
      xval = xp[(size_t)tn * 32];
    }

    f32x4 acc[4][2];
    const bf16x8 a0 = *reinterpret_cast<const bf16x8*>(ArowC + 0 * 32 + akoff);
    const bf16x8 a1 = *reinterpret_cast<const bf16x8*>(ArowC + 1 * 32 + akoff);
    const bf16x8 a2 = *reinterpret_cast<const bf16x8*>(ArowC + 2 * 32 + akoff);
    const bf16x8 a3 = *reinterpret_cast<const bf16x8*>(ArowC + 3 * 32 + akoff);
    __builtin_amdgcn_s_setprio(1);
    {
      acc[0][0] = __builtin_amdgcn_mfma_f32_16x16x32_bf16(a0, Bf[0][0], z4, 0, 0, 0);
      acc[0][1] = __builtin_amdgcn_mfma_f32_16x16x32_bf16(a0, Bf[0][1], z4, 0, 0, 0);
      acc[1][0] = __builtin_amdgcn_mfma_f32_16x16x32_bf16(a0, Bg[0][0], z4, 0, 0, 0);
      acc[1][1] = __builtin_amdgcn_mfma_f32_16x16x32_bf16(a0, Bg[0][1], z4, 0, 0, 0);
      acc[2][0] = __builtin_amdgcn_mfma_f32_16x16x32_bf16(a0, Bo[0][0], z4, 0, 0, 0);
      acc[2][1] = __builtin_amdgcn_mfma_f32_16x16x32_bf16(a0, Bo[0][1], z4, 0, 0, 0);
    }
    {
      const bf16x8 aa[3] = {a1, a2, a3};
#pragma unroll
      for (int ks = 1; ks < 4; ++ks) {
        const bf16x8 a = aa[ks - 1];
        acc[0][0] = __builtin_amdgcn_mfma_f32_16x16x32_bf16(a, Bf[ks][0], acc[0][0], 0, 0, 0);
        acc[0][1] = __builtin_amdgcn_mfma_f32_16x16x32_bf16(a, Bf[ks][1], acc[0][1], 0, 0, 0);
        acc[1][0] = __builtin_amdgcn_mfma_f32_16x16x32_bf16(a, Bg[ks][0], acc[1][0], 0, 0, 0);
        acc[1][1] = __builtin_amdgcn_mfma_f32_16x16x32_bf16(a, Bg[ks][1], acc[1][1], 0, 0, 0);
        acc[2][0] = __builtin_amdgcn_mfma_f32_16x16x32_bf16(a, Bo[ks][0], acc[2][0], 0, 0, 0);
        acc[2][1] = __builtin_amdgcn_mfma_f32_16x16x32_bf16(a, Bo[ks][1], acc[2][1], 0, 0, 0);
      }
    }
#pragma unroll
    for (int ks = 4; ks < 8; ++ks) {
      const bf16x8 a = *reinterpret_cast<const bf16x8*>(ArowC + ks * 32 + akoff);
      acc[0][0] = __builtin_amdgcn_mfma_f32_16x16x32_bf16(a, Bf[ks][0], acc[0][0], 0, 0, 0);
      acc[0][1] = __builtin_amdgcn_mfma_f32_16x16x32_bf16(a, Bf[ks][1], acc[0][1], 0, 0, 0);
      acc[1][0] = __builtin_amdgcn_mfma_f32_16x16x32_bf16(a, Bg[ks][0], acc[1][0], 0, 0, 0);
      acc[1][1] = __builtin_amdgcn_mfma_f32_16x16x32_bf16(a, Bg[ks][1], acc[1][1], 0, 0, 0);
      if (ks < 7) {
        acc[2][0] = __builtin_amdgcn_mfma_f32_16x16x32_bf16(a, Bo[ks][0], acc[2][0], 0, 0, 0);
        acc[2][1] = __builtin_amdgcn_mfma_f32_16x16x32_bf16(a, Bo[ks][1], acc[2][1], 0, 0, 0);
      } else {
        const bf16x8 b0 = *reinterpret_cast<const bf16x8*>(bo7 + 0 * 512 + l * 8);
        const bf16x8 b1 = *reinterpret_cast<const bf16x8*>(bo7 + 1 * 512 + l * 8);
        acc[2][0] = __builtin_amdgcn_mfma_f32_16x16x32_bf16(a, b0, acc[2][0], 0, 0, 0);
        acc[2][1] = __builtin_amdgcn_mfma_f32_16x16x32_bf16(a, b1, acc[2][1], 0, 0, 0);
      }
    }
    {
      const bf16x8 ax = *reinterpret_cast<const bf16x8*>(ArowC + 256 + akoff);
#pragma unroll
      for (int g = 0; g < 3; ++g) {
#pragma unroll
        for (int nt = 0; nt < 2; ++nt) {
          const bf16x8 b = *reinterpret_cast<const bf16x8*>(bxw + (g * 2 + nt) * 512 + l * 8);
          acc[g][nt] = __builtin_amdgcn_mfma_f32_16x16x32_bf16(ax, b, acc[g][nt], 0, 0, 0);
        }
      }
#pragma unroll
      for (int nt = 0; nt < 2; ++nt) {
        const bf16x8 b = *reinterpret_cast<const bf16x8*>(bxw + (6 + nt) * 512 + l * 8);
        f32x4 cbv; cbv[0] = bias[3][nt]; cbv[1] = bias[3][nt]; cbv[2] = bias[3][nt]; cbv[3] = bias[3][nt];
        acc[3][nt] = __builtin_amdgcn_mfma_f32_16x16x32_bf16(ax, b, cbv, 0, 0, 0);
      }
    }
    __builtin_amdgcn_s_setprio(0);

    float po = 0.0f;
    short hpk[2];
#pragma unroll
    for (int nt = 0; nt < 2; ++nt) {
      const float fpre = acc[0][nt][0] + bias[0][nt];
      const float gpre = acc[1][nt][0] + bias[1][nt];
      const float opre = acc[2][nt][0] + bias[2][nt];
      const float ipre = acc[3][nt][0];
      const float sf = sigm(fpre);
      const float tg = tanh_(gpre);
      const float so = sigm(opre);
      const float si = sigm(ipre);
      const float c  = sf * cst[nt] + si * tg;
      cst[nt] = c;
      const float hv = so * tanh_(c);
      hpk[nt] = f2bf(hv);
      po += so * woutv[nt];
    }

    Anxt[(4 * lg) * FASTR + (n0 + lr)]      = hpk[0];
    Anxt[(4 * lg) * FASTR + (n0 + 16 + lr)] = hpk[1];
    if (xstage) Anxt[(4 * ((tid >> 5) & 3)) * FASTR + 256 + (tid & 31)] = f2bf(xval);

    po += __shfl_xor(po, 1, 64);
    po += __shfl_xor(po, 2, 64);
    if ((lr & 3) == 0) out_part[cur][lg][w * 4 + (lr >> 2)] = po;

    wg_barrier_lgkm();
  }

  if (w == 0 && l < 4) {
    float s = boutv;
#pragma unroll
    for (int ww = 0; ww < 32; ++ww) s += out_part[(T_LEN - 1) & 1][l][ww];
    out[(size_t)(wg * 4 + l) * T_LEN + (T_LEN - 1)] = s;
  }
}

extern "C" void kernel_launch(void* const* d_in, const int* in_sizes, int n_in,
                              void* d_out, int out_size, void* d_ws, size_t ws_size,
                              hipStream_t stream) {
  const float* x    = (const float*)d_in[0];
  const float* c0   = (const float*)d_in[1];
  const float* h0   = (const float*)d_in[2];
  const float* Wi   = (const float*)d_in[3];
  const float* bi   = (const float*)d_in[4];
  const float* Wfx  = (const float*)d_in[5];
  const float* bfx  = (const float*)d_in[6];
  const float* Wfh  = (const float*)d_in[7];
  const float* bfh  = (const float*)d_in[8];
  const float* Wgx  = (const float*)d_in[9];
  const float* bgx  = (const float*)d_in[10];
  const float* Wgh  = (const float*)d_in[11];
  const float* bgh  = (const float*)d_in[12];
  const float* Wox  = (const float*)d_in[13];
  const float* box_ = (const float*)d_in[14];
  const float* Woh  = (const float*)d_in[15];
  const float* boh  = (const float*)d_in[16];
  const float* Wout = (const float*)d_in[17];
  const float* bout = (const float*)d_in[18];

  // P bytes = 32 WG x 8 waves x tc x 512 shorts x 2B = tc * 256 KiB
  int tc = 0;
  for (int cand = T_LEN; cand >= 64; cand >>= 1) {
    if (ws_size >= (size_t)cand * 262144) { tc = cand; break; }
  }

  if (tc) {
    ealstm_pp<<<dim3(32), dim3(512), 0, stream>>>(
        x, c0, h0, Wi, bi, Wfx, bfx, Wfh, bfh,
        Wgx, bgx, Wgh, bgh, Wox, box_, Woh, boh, Wout, bout,
        (float*)d_out, (unsigned short*)d_ws, tc);
  } else {
    ealstm_fb<<<dim3(32), dim3(512), 0, stream>>>(
        x, c0, h0, Wi, bi, Wfx, bfx, Wfh, bfh,
        Wgx, bgx, Wgh, bgh, Wox, box_, Woh, boh, Wout, bout,
        (float*)d_out);
  }
}

// Round 16
// 4661.647 us; speedup vs baseline: 1.3974x; 1.3974x over previous
//
#include <hip/hip_runtime.h>
#include <hip/hip_bf16.h>

// EA-LSTM persistent kernel for MI355X (gfx950), round 16.
// B=128, T=2048, DYN=8, STAT=24, H=256, OUT=1.
// R14 body + x-projections precomputed IN LDS, 8 steps at a time (tc=8).
// 32 WGs x 512 thr (8 waves, 2/SIMD). Batch row b staged at A-row 4b (MFMA D
// r==0 -> 1 gate-set per lane,nt); wave w owns ch [w*32,w*32+32).
// Phase A (per 8-step chunk, per wave): ONE M=16 tile packs 2 rows x 8 t
// (x2 tiles -> 4 rows x 8 t), 16 MFMAs total (amortized 2/step vs 8/step
// at 25% M-efficiency in R14) -> P_sh[w][t][row][lr] = 16B
// {f,f,g,g,o,o,sig(i),sig(i)} with ALL biases baked in. Wave-private ->
// no barrier, lgkmcnt only. x for chunk k+1 prefetched to regs at chunk k.
// Phase B step: 48 MFMAs (f,g ks0..7 + o ks0..6 regs; o-ks7 LDS), 11 LDS
// b128 reads, epilogue without bias adds (i pre-sigmoided), lgkm-only
// barrier, setprio, po 2-step reduce, wave0 shadowed finalize.
// No workspace needed.

#define T_LEN 2048
#define HD 256

typedef __attribute__((ext_vector_type(8))) short bf16x8;
typedef __attribute__((ext_vector_type(4))) float f32x4;
typedef __attribute__((ext_vector_type(4))) unsigned int u32x4;

#define LOG2E 1.4426950408889634f

__device__ __forceinline__ short f2bf(float f) {
  unsigned u = __float_as_uint(f);
  unsigned r = (u + 0x7fffu + ((u >> 16) & 1u)) >> 16;
  return (short)r;
}

__device__ __forceinline__ bf16x8 loadw8(const float* p) {
  bf16x8 r;
#pragma unroll
  for (int i = 0; i < 8; ++i) r[i] = f2bf(p[i]);
  return r;
}

__device__ __forceinline__ bf16x8 cvt8(float4 a, float4 b) {
  bf16x8 r;
  r[0] = f2bf(a.x); r[1] = f2bf(a.y); r[2] = f2bf(a.z); r[3] = f2bf(a.w);
  r[4] = f2bf(b.x); r[5] = f2bf(b.y); r[6] = f2bf(b.z); r[7] = f2bf(b.w);
  return r;
}

__device__ __forceinline__ float sigm(float x) {
  float e = __builtin_amdgcn_exp2f(-LOG2E * x);
  return __builtin_amdgcn_rcpf(1.0f + e);
}

// clamp-free tanh: 1 - 2/(e^{2x}+1); saturates to +/-1, NaN-free.
__device__ __forceinline__ float tanh_(float x) {
  float e = __builtin_amdgcn_exp2f((2.0f * LOG2E) * x);
  return 1.0f - 2.0f * __builtin_amdgcn_rcpf(e + 1.0f);
}

// bf16 short idx (0..7) out of a 16B packed block
__device__ __forceinline__ float punp16(u32x4 p, int idx) {
  unsigned d = p[idx >> 1];
  return __uint_as_float((idx & 1) ? (d & 0xffff0000u) : (d << 16));
}

// Workgroup barrier draining ONLY LDS ops (not vmem).
__device__ __forceinline__ void wg_barrier_lgkm() {
  asm volatile("s_waitcnt lgkmcnt(0)" ::: "memory");
  __builtin_amdgcn_s_barrier();
  __builtin_amdgcn_sched_barrier(0);
}

// A tile: 16 rows x 264 cols bf16 (h only). Valid batch rows at A-rows {0,4,8,12}.
#define ASTR 264
#define ABUF (16 * ASTR)

__global__ __launch_bounds__(512, 2) void ealstm_kernel(
    const float* __restrict__ x, const float* __restrict__ c0, const float* __restrict__ h0,
    const float* __restrict__ Wi, const float* __restrict__ bi,
    const float* __restrict__ Wfx, const float* __restrict__ bfx,
    const float* __restrict__ Wfh, const float* __restrict__ bfh,
    const float* __restrict__ Wgx, const float* __restrict__ bgx,
    const float* __restrict__ Wgh, const float* __restrict__ bgh,
    const float* __restrict__ Wox, const float* __restrict__ box_,
    const float* __restrict__ Woh, const float* __restrict__ boh,
    const float* __restrict__ Wout, const float* __restrict__ bout,
    float* __restrict__ out)
{
  __shared__ __attribute__((aligned(16))) short A_sh[2 * ABUF];        // 16896 B
  __shared__ __attribute__((aligned(16))) short Bo7_sh[8 * 2 * 512];   // 16384 B
  __shared__ __attribute__((aligned(16))) short P_sh[8 * 8 * 512];     // 65536 B
  __shared__ float out_part[2][4][32];                                 // 1024 B

  const int tid = threadIdx.x;
  const int w   = tid >> 6;   // wave 0..7, owns ch [w*32, w*32+32)
  const int l   = tid & 63;
  const int lr  = l & 15;
  const int lg  = l >> 4;     // activation row = lg (A-row trick)
  const int n0  = w * 32;
  const int wg  = blockIdx.x; // 4-row batch block

  // ---- x-projection B-frags (K=32: dyn 0..7, stat 8..31) + combined biases ----
  bf16x8 Bw[4][2];
  float cb[4][2];
  {
    bf16x8 z = (bf16x8)(short)0;
#pragma unroll
    for (int nt = 0; nt < 2; ++nt) {
      const int n = n0 + nt * 16 + lr;
      Bw[0][nt] = (lg == 0) ? loadw8(Wfx + n * 8) : z;
      Bw[1][nt] = (lg == 0) ? loadw8(Wgx + n * 8) : z;
      Bw[2][nt] = (lg == 0) ? loadw8(Wox + n * 8) : z;
      Bw[3][nt] = (lg >= 1) ? loadw8(Wi + n * 24 + (lg - 1) * 8) : z;
      cb[0][nt] = bfx[n] + bfh[n];
      cb[1][nt] = bgx[n] + bgh[n];
      cb[2][nt] = box_[n] + boh[n];
      cb[3][nt] = bi[n];
    }
  }

  // ---- register-resident recurrent weights: f,g ks0..7; o ks0..6 ----
  bf16x8 Bf[8][2], Bg[8][2], Bo[7][2];
#pragma unroll
  for (int ks = 0; ks < 8; ++ks) {
#pragma unroll
    for (int nt = 0; nt < 2; ++nt) {
      const int n = n0 + nt * 16 + lr;
      const int k = ks * 32 + lg * 8;
      Bf[ks][nt] = loadw8(Wfh + n * HD + k);
      Bg[ks][nt] = loadw8(Wgh + n * HD + k);
      if (ks < 7) Bo[ks][nt] = loadw8(Woh + n * HD + k);
    }
  }
  // ---- LDS-resident: o ks7 ----
  short* bo7 = Bo7_sh + w * 1024;
#pragma unroll
  for (int nt = 0; nt < 2; ++nt) {
    const int n = n0 + nt * 16 + lr;
    bf16x8 fr = loadw8(Woh + n * HD + 7 * 32 + lg * 8);
    *reinterpret_cast<bf16x8*>(bo7 + nt * 512 + l * 8) = fr;
  }

  // ---- Wout, c-state ----
  float woutv[2], cst[2];
#pragma unroll
  for (int nt = 0; nt < 2; ++nt) {
    const int n = n0 + nt * 16 + lr;
    woutv[nt] = Wout[n];
    cst[nt]   = c0[n];
  }
  const float boutv = bout[0];

  // ---- zero both A buffers; stage h0 at A-rows {0,4,8,12} ----
  for (int idx = tid; idx < 2 * ABUF; idx += 512) A_sh[idx] = 0;
  __syncthreads();
  for (int idx = tid; idx < 4 * 256; idx += 512) {
    A_sh[(4 * (idx >> 8)) * ASTR + (idx & 255)] = f2bf(h0[idx & 255]);
  }
  __syncthreads();

  short* Pl = P_sh + w * 4096;  // wave-private P (8 t x 4 rows x 16 lr x 8 shorts)
  const int akoff = lg * 8;
  const f32x4 z4 = {0.f, 0.f, 0.f, 0.f};

  // x address for the packed Phase-A tile: tile in {0,1}; A-row m=lr ->
  // (batch row = wg*4 + tile*2 + (lr>>3), t = t0c + (lr&7)), k = lg*8..+8.
  const size_t xoff0 = ((size_t)(wg * 4 + 0 + (lr >> 3)) * T_LEN + (lr & 7)) * 32 + akoff;
  const size_t xoff1 = ((size_t)(wg * 4 + 2 + (lr >> 3)) * T_LEN + (lr & 7)) * 32 + akoff;

  // prefetch x for chunk 0
  float4 xbuf[4];
  xbuf[0] = *reinterpret_cast<const float4*>(x + xoff0);
  xbuf[1] = *reinterpret_cast<const float4*>(x + xoff0 + 4);
  xbuf[2] = *reinterpret_cast<const float4*>(x + xoff1);
  xbuf[3] = *reinterpret_cast<const float4*>(x + xoff1 + 4);

  for (int t0c = 0; t0c < T_LEN; t0c += 8) {
    // ============== Phase A: precompute P for [t0c, t0c+8) ==============
    {
      const bf16x8 aT0 = cvt8(xbuf[0], xbuf[1]);
      const bf16x8 aT1 = cvt8(xbuf[2], xbuf[3]);
      // issue next chunk's x loads (consumed 8 steps from now)
      const size_t tnoff = (size_t)((t0c + 8 < T_LEN) ? (t0c + 8) : t0c) * 32;
      xbuf[0] = *reinterpret_cast<const float4*>(x + xoff0 + tnoff);
      xbuf[1] = *reinterpret_cast<const float4*>(x + xoff0 + tnoff + 4);
      xbuf[2] = *reinterpret_cast<const float4*>(x + xoff1 + tnoff);
      xbuf[3] = *reinterpret_cast<const float4*>(x + xoff1 + tnoff + 4);

      const bf16x8 aTs[2] = {aT0, aT1};
#pragma unroll
      for (int tile = 0; tile < 2; ++tile) {
        f32x4 pacc[4][2];
#pragma unroll
        for (int g = 0; g < 4; ++g) {
#pragma unroll
          for (int nt = 0; nt < 2; ++nt) {
            f32x4 cbs; cbs[0] = cb[g][nt]; cbs[1] = cb[g][nt]; cbs[2] = cb[g][nt]; cbs[3] = cb[g][nt];
            pacc[g][nt] = __builtin_amdgcn_mfma_f32_16x16x32_bf16(aTs[tile], Bw[g][nt], cbs, 0, 0, 0);
          }
        }
#pragma unroll
        for (int r = 0; r < 4; ++r) {
          const int mq = lg * 4 + r;  // D row -> (t = mq&7, row = tile*2 + (mq>>3))
          bf16x8 pk;
          pk[0] = f2bf(pacc[0][0][r]); pk[1] = f2bf(pacc[0][1][r]);
          pk[2] = f2bf(pacc[1][0][r]); pk[3] = f2bf(pacc[1][1][r]);
          pk[4] = f2bf(pacc[2][0][r]); pk[5] = f2bf(pacc[2][1][r]);
          pk[6] = f2bf(sigm(pacc[3][0][r])); pk[7] = f2bf(sigm(pacc[3][1][r]));
          *reinterpret_cast<bf16x8*>(Pl + (mq & 7) * 512 + (tile * 2 + (mq >> 3)) * 128 + lr * 8) = pk;
        }
      }
    }

    // ============== Phase B: 8 recurrence steps ==============
#pragma unroll 1
    for (int tl = 0; tl < 8; ++tl) {
      const int t   = t0c + tl;
      const int cur = t & 1;
      const short* ArowC = A_sh + cur * ABUF + lr * ASTR;
      short* Anxt = A_sh + (cur ^ 1) * ABUF;

      // P for this step (wave-private LDS; latency hidden under MFMAs)
      const u32x4 pc = *reinterpret_cast<const u32x4*>(Pl + tl * 512 + lg * 128 + lr * 8);

      // finalize previous step's output (hidden under this step's MFMA phase)
      if (t > 0 && w == 0 && l < 4) {
        float s = boutv;
#pragma unroll
        for (int ww = 0; ww < 32; ++ww) s += out_part[cur ^ 1][l][ww];
        out[(size_t)(wg * 4 + l) * T_LEN + (t - 1)] = s;
      }

      // ---- h K-loop (48 MFMAs); setprio around the cluster ----
      f32x4 acc[3][2];
      const bf16x8 a0 = *reinterpret_cast<const bf16x8*>(ArowC + 0 * 32 + akoff);
      const bf16x8 a1 = *reinterpret_cast<const bf16x8*>(ArowC + 1 * 32 + akoff);
      const bf16x8 a2 = *reinterpret_cast<const bf16x8*>(ArowC + 2 * 32 + akoff);
      const bf16x8 a3 = *reinterpret_cast<const bf16x8*>(ArowC + 3 * 32 + akoff);
      __builtin_amdgcn_s_setprio(1);
      {
        acc[0][0] = __builtin_amdgcn_mfma_f32_16x16x32_bf16(a0, Bf[0][0], z4, 0, 0, 0);
        acc[0][1] = __builtin_amdgcn_mfma_f32_16x16x32_bf16(a0, Bf[0][1], z4, 0, 0, 0);
        acc[1][0] = __builtin_amdgcn_mfma_f32_16x16x32_bf16(a0, Bg[0][0], z4, 0, 0, 0);
        acc[1][1] = __builtin_amdgcn_mfma_f32_16x16x32_bf16(a0, Bg[0][1], z4, 0, 0, 0);
        acc[2][0] = __builtin_amdgcn_mfma_f32_16x16x32_bf16(a0, Bo[0][0], z4, 0, 0, 0);
        acc[2][1] = __builtin_amdgcn_mfma_f32_16x16x32_bf16(a0, Bo[0][1], z4, 0, 0, 0);
      }
      {
        const bf16x8 aa[3] = {a1, a2, a3};
#pragma unroll
        for (int ks = 1; ks < 4; ++ks) {
          const bf16x8 a = aa[ks - 1];
          acc[0][0] = __builtin_amdgcn_mfma_f32_16x16x32_bf16(a, Bf[ks][0], acc[0][0], 0, 0, 0);
          acc[0][1] = __builtin_amdgcn_mfma_f32_16x16x32_bf16(a, Bf[ks][1], acc[0][1], 0, 0, 0);
          acc[1][0] = __builtin_amdgcn_mfma_f32_16x16x32_bf16(a, Bg[ks][0], acc[1][0], 0, 0, 0);
          acc[1][1] = __builtin_amdgcn_mfma_f32_16x16x32_bf16(a, Bg[ks][1], acc[1][1], 0, 0, 0);
          acc[2][0] = __builtin_amdgcn_mfma_f32_16x16x32_bf16(a, Bo[ks][0], acc[2][0], 0, 0, 0);
          acc[2][1] = __builtin_amdgcn_mfma_f32_16x16x32_bf16(a, Bo[ks][1], acc[2][1], 0, 0, 0);
        }
      }
#pragma unroll
      for (int ks = 4; ks < 8; ++ks) {
        const bf16x8 a = *reinterpret_cast<const bf16x8*>(ArowC + ks * 32 + akoff);
        acc[0][0] = __builtin_amdgcn_mfma_f32_16x16x32_bf16(a, Bf[ks][0], acc[0][0], 0, 0, 0);
        acc[0][1] = __builtin_amdgcn_mfma_f32_16x16x32_bf16(a, Bf[ks][1], acc[0][1], 0, 0, 0);
        acc[1][0] = __builtin_amdgcn_mfma_f32_16x16x32_bf16(a, Bg[ks][0], acc[1][0], 0, 0, 0);
        acc[1][1] = __builtin_amdgcn_mfma_f32_16x16x32_bf16(a, Bg[ks][1], acc[1][1], 0, 0, 0);
        if (ks < 7) {
          acc[2][0] = __builtin_amdgcn_mfma_f32_16x16x32_bf16(a, Bo[ks][0], acc[2][0], 0, 0, 0);
          acc[2][1] = __builtin_amdgcn_mfma_f32_16x16x32_bf16(a, Bo[ks][1], acc[2][1], 0, 0, 0);
        } else {
          const bf16x8 b0 = *reinterpret_cast<const bf16x8*>(bo7 + 0 * 512 + l * 8);
          const bf16x8 b1 = *reinterpret_cast<const bf16x8*>(bo7 + 1 * 512 + l * 8);
          acc[2][0] = __builtin_amdgcn_mfma_f32_16x16x32_bf16(a, b0, acc[2][0], 0, 0, 0);
          acc[2][1] = __builtin_amdgcn_mfma_f32_16x16x32_bf16(a, b1, acc[2][1], 0, 0, 0);
        }
      }
      __builtin_amdgcn_s_setprio(0);

      // ---- activations (x-proj + biases in pc; i pre-sigmoided) ----
      float po = 0.0f;
      short hpk[2];
#pragma unroll
      for (int nt = 0; nt < 2; ++nt) {
        const float fpre = acc[0][nt][0] + punp16(pc, 0 + nt);
        const float gpre = acc[1][nt][0] + punp16(pc, 2 + nt);
        const float opre = acc[2][nt][0] + punp16(pc, 4 + nt);
        const float si   = punp16(pc, 6 + nt);
        const float sf = sigm(fpre);
        const float tg = tanh_(gpre);
        const float so = sigm(opre);
        const float c  = sf * cst[nt] + si * tg;
        cst[nt] = c;
        const float hv = so * tanh_(c);
        hpk[nt] = f2bf(hv);
        po += so * woutv[nt];
      }

      // h-writes into ALTERNATE buffer at A-row 4*lg
      Anxt[(4 * lg) * ASTR + (n0 + lr)]      = hpk[0];
      Anxt[(4 * lg) * ASTR + (n0 + 16 + lr)] = hpk[1];

      // po partial-reduce: 2 shuffle steps; 4 partials per (row, wave)
      po += __shfl_xor(po, 1, 64);
      po += __shfl_xor(po, 2, 64);
      if ((lr & 3) == 0) out_part[cur][lg][w * 4 + (lr >> 2)] = po;

      wg_barrier_lgkm();  // single per-step barrier, LDS-drain only
    }
  }

  // final output
  if (w == 0 && l < 4) {
    float s = boutv;
#pragma unroll
    for (int ww = 0; ww < 32; ++ww) s += out_part[(T_LEN - 1) & 1][l][ww];
    out[(size_t)(wg * 4 + l) * T_LEN + (T_LEN - 1)] = s;
  }
}

extern "C" void kernel_launch(void* const* d_in, const int* in_sizes, int n_in,
                              void* d_out, int out_size, void* d_ws, size_t ws_size,
                              hipStream_t stream) {
  const float* x    = (const float*)d_in[0];
  const float* c0   = (const float*)d_in[1];
  const float* h0   = (const float*)d_in[2];
  const float* Wi   = (const float*)d_in[3];
  const float* bi   = (const float*)d_in[4];
  const float* Wfx  = (const float*)d_in[5];
  const float* bfx  = (const float*)d_in[6];
  const float* Wfh  = (const float*)d_in[7];
  const float* bfh  = (const float*)d_in[8];
  const float* Wgx  = (const float*)d_in[9];
  const float* bgx  = (const float*)d_in[10];
  const float* Wgh  = (const float*)d_in[11];
  const float* bgh  = (const float*)d_in[12];
  const float* Wox  = (const float*)d_in[13];
  const float* box_ = (const float*)d_in[14];
  const float* Woh  = (const float*)d_in[15];
  const float* boh  = (const float*)d_in[16];
  const float* Wout = (const float*)d_in[17];
  const float* bout = (const float*)d_in[18];

  ealstm_kernel<<<dim3(32), dim3(512), 0, stream>>>(
      x, c0, h0, Wi, bi, Wfx, bfx, Wfh, bfh,
      Wgx, bgx, Wgh, bgh, Wox, box_, Woh, boh, Wout, bout,
      (float*)d_out);
}